// Round 1
// baseline (802.530 us; speedup 1.0000x reference)
//
#include <hip/hip_runtime.h>
#include <hip/hip_bf16.h>

// Problem: B=8, T=2048, D=2048.
//   avg = cumsum(x, axis=T) / (t+1)
//   gates = concat(x, avg) @ W^T + b    (W: [4096][4096])
//   out0 = sigmoid(gates[:, :2048]) * x + sigmoid(gates[:, 2048:]) * avg
//   outputs: [out0 (fp32, 8*2048*2048)] ++ [avg (fp32, 8*2048*2048)]

#define Bb 8
#define Tt 2048
#define Dd 2048
#define Mm (Bb * Tt)       // 16384 rows
#define Kk 4096            // concat width
#define NC 32              // T-chunks
#define CT 64              // t per chunk

typedef __bf16 bf16x8 __attribute__((ext_vector_type(8)));
typedef float f32x4 __attribute__((ext_vector_type(4)));

__device__ __forceinline__ void gload16(const void* g, void* l) {
    __builtin_amdgcn_global_load_lds(
        (const __attribute__((address_space(1))) unsigned int*)g,
        (__attribute__((address_space(3))) unsigned int*)l, 16, 0, 0);
}

// ---------------- K1: W fp32 -> bf16 ----------------
__global__ void wconv_kernel(const float* __restrict__ W,
                             unsigned short* __restrict__ Wb, long n) {
    long i = ((long)blockIdx.x * blockDim.x + threadIdx.x) * 4;
    long stride = (long)gridDim.x * blockDim.x * 4;
    for (; i < n; i += stride) {
        float4 v = *(const float4*)(W + i);
        __hip_bfloat16 a = __float2bfloat16(v.x);
        __hip_bfloat16 b = __float2bfloat16(v.y);
        __hip_bfloat16 c = __float2bfloat16(v.z);
        __hip_bfloat16 d = __float2bfloat16(v.w);
        ushort4 u;
        u.x = *(unsigned short*)&a; u.y = *(unsigned short*)&b;
        u.z = *(unsigned short*)&c; u.w = *(unsigned short*)&d;
        *(ushort4*)(Wb + i) = u;
    }
}

// ---------------- K2: per-chunk sums ----------------
// grid (Bb*NC, Dd/256), block 256. S[b][c][d] = sum over chunk c of x[b,t,d]
__global__ void ksum_kernel(const float* __restrict__ X, float* __restrict__ S) {
    int d = blockIdx.y * 256 + threadIdx.x;
    int bc = blockIdx.x;
    int b = bc >> 5, c = bc & 31;
    const float* p = X + ((long)(b * Tt + c * CT)) * Dd + d;
    float s = 0.f;
#pragma unroll 8
    for (int t = 0; t < CT; ++t) s += p[(long)t * Dd];
    S[(long)bc * Dd + d] = s;
}

// ---------------- K3: scan + emit avg fp32 + gating_in bf16 ----------------
__global__ void kscan_kernel(const float* __restrict__ X, const float* __restrict__ S,
                             float* __restrict__ AVG, unsigned short* __restrict__ Gin) {
    int d = blockIdx.y * 256 + threadIdx.x;
    int bc = blockIdx.x;
    int b = bc >> 5, c = bc & 31;
    const float* Sp = S + (long)(b * NC) * Dd + d;
    float run = 0.f;
    for (int cc = 0; cc < c; ++cc) run += Sp[(long)cc * Dd];
    const float* p = X + ((long)(b * Tt + c * CT)) * Dd + d;
    long row = (long)b * Tt + c * CT;
    for (int tt = 0; tt < CT; ++tt) {
        float x = p[(long)tt * Dd];
        run += x;
        float av = run / (float)(c * CT + tt + 1);
        long r = row + tt;
        AVG[r * Dd + d] = av;
        __hip_bfloat16 xb = __float2bfloat16(x);
        __hip_bfloat16 ab = __float2bfloat16(av);
        Gin[r * 4096 + d] = *(unsigned short*)&xb;
        Gin[r * 4096 + 2048 + d] = *(unsigned short*)&ab;
    }
}

// ---------------- K4: fused dual-gate GEMM + epilogue ----------------
// C_i[m][n] = sum_k Gin[m][k] * Wb[n][k]        (n in [n0, n0+128))
// C_f[m][n] = sum_k Gin[m][k] * Wb[n+2048][k]
// out[m][n] = sig(C_i + bias[n]) * x[m][n] + sig(C_f + bias[n+2048]) * avg[m][n]
// 128x128 tile, BK=32, 8 waves (2x4), each wave: 64x32 region, dual acc.
__global__ __launch_bounds__(512, 2) void gemm_fused_kernel(
    const unsigned short* __restrict__ Gin,  // [16384][4096] bf16
    const unsigned short* __restrict__ Wb,   // [4096][4096] bf16
    const float* __restrict__ bias,          // [4096]
    const float* __restrict__ X,             // [16384][2048]
    const float* __restrict__ AVG,           // [16384][2048]
    float* __restrict__ OUT)                 // [16384][2048]
{
    __shared__ unsigned short sA[128 * 32];
    __shared__ unsigned short sBi[128 * 32];
    __shared__ unsigned short sBf[128 * 32];

    const int tid = threadIdx.x;
    const int w = tid >> 6, l = tid & 63;
    const int wm = w >> 2, wn = w & 3;   // 2 (M) x 4 (N) waves

    const long m0 = (long)blockIdx.x * 128;
    const int n0 = blockIdx.y * 128;

    // staging addresses: tile row = tid/4, 16B column chunk = tid%4
    const char* gA  = (const char*)Gin + (m0 + (tid >> 2)) * 8192 + (tid & 3) * 16;
    const char* gBi = (const char*)Wb + (long)(n0 + (tid >> 2)) * 8192 + (tid & 3) * 16;
    const char* gBf = (const char*)Wb + (long)(n0 + 2048 + (tid >> 2)) * 8192 + (tid & 3) * 16;
    // wave-uniform LDS staging bases (dest = base + lane*16)
    char* lA  = (char*)sA  + w * 1024;
    char* lBi = (char*)sBi + w * 1024;
    char* lBf = (char*)sBf + w * 1024;

    f32x4 acc_i[4][2] = {};
    f32x4 acc_f[4][2] = {};

    const int lm = l & 15;               // fragment row within 16
    const int lk = (l >> 4) * 16;        // fragment k-byte offset within row (32*2B rows)

    for (int kt = 0; kt < 128; ++kt) {
        const int koff = kt * 64;        // BK*2 bytes
        gload16(gA + koff, lA);
        gload16(gBi + koff, lBi);
        gload16(gBf + koff, lBf);
        __syncthreads();

        bf16x8 a[4], bi[2], bf_[2];
#pragma unroll
        for (int i = 0; i < 4; ++i)
            a[i] = *(const bf16x8*)((const char*)sA + (wm * 64 + i * 16 + lm) * 64 + lk);
#pragma unroll
        for (int j = 0; j < 2; ++j) {
            bi[j]  = *(const bf16x8*)((const char*)sBi + (wn * 32 + j * 16 + lm) * 64 + lk);
            bf_[j] = *(const bf16x8*)((const char*)sBf + (wn * 32 + j * 16 + lm) * 64 + lk);
        }
#pragma unroll
        for (int i = 0; i < 4; ++i)
#pragma unroll
            for (int j = 0; j < 2; ++j) {
                acc_i[i][j] = __builtin_amdgcn_mfma_f32_16x16x32_bf16(a[i], bi[j], acc_i[i][j], 0, 0, 0);
                acc_f[i][j] = __builtin_amdgcn_mfma_f32_16x16x32_bf16(a[i], bf_[j], acc_f[i][j], 0, 0, 0);
            }
        __syncthreads();
    }

    // epilogue: C/D layout: col = lane&15, row = (lane>>4)*4 + reg
    const int col0 = n0 + wn * 32;
#pragma unroll
    for (int i = 0; i < 4; ++i) {
        long rbase = m0 + wm * 64 + i * 16 + (l >> 4) * 4;
#pragma unroll
        for (int j = 0; j < 2; ++j) {
            int d = col0 + j * 16 + (l & 15);
            float bi_ = bias[d];
            float bf2 = bias[d + 2048];
#pragma unroll
            for (int r = 0; r < 4; ++r) {
                long idx = (rbase + r) * 2048 + d;
                float gi = acc_i[i][j][r] + bi_;
                float gf = acc_f[i][j][r] + bf2;
                float x = X[idx];
                float av = AVG[idx];
                float si = 1.f / (1.f + __expf(-gi));
                float sf = 1.f / (1.f + __expf(-gf));
                OUT[idx] = si * x + sf * av;
            }
        }
    }
}

extern "C" void kernel_launch(void* const* d_in, const int* in_sizes, int n_in,
                              void* d_out, int out_size, void* d_ws, size_t ws_size,
                              hipStream_t stream) {
    const float* X = (const float*)d_in[0];     // layer_in [8][2048][2048]
    const float* W = (const float*)d_in[1];     // W_gate [4096][4096]
    const float* bias = (const float*)d_in[2];  // b_gate [4096]

    float* OUT = (float*)d_out;                       // gating_out
    float* AVG = OUT + (long)Mm * Dd;                 // average_out

    char* ws = (char*)d_ws;
    unsigned short* Wb  = (unsigned short*)ws;                      // 33,554,432 B
    unsigned short* Gin = (unsigned short*)(ws + 33554432);         // 134,217,728 B
    float* S = (float*)(ws + 33554432 + 134217728);                 // 2,097,152 B

    wconv_kernel<<<2048, 256, 0, stream>>>(W, Wb, (long)Kk * Kk);
    ksum_kernel<<<dim3(Bb * NC, Dd / 256), 256, 0, stream>>>(X, S);
    kscan_kernel<<<dim3(Bb * NC, Dd / 256), 256, 0, stream>>>(X, S, AVG, Gin);
    gemm_fused_kernel<<<dim3(Mm / 128, Dd / 128), 512, 0, stream>>>(Gin, Wb, bias, X, AVG, OUT);
}

// Round 2
// 690.156 us; speedup vs baseline: 1.1628x; 1.1628x over previous
//
#include <hip/hip_runtime.h>
#include <hip/hip_bf16.h>

// B=8, T=2048, D=2048.
//   avg = cumsum(x, axis=T) / (t+1)
//   gates = concat(x, avg) @ W^T + b    (W: [4096][4096])
//   out0 = sig(gates[:, :2048]) * x + sig(gates[:, 2048:]) * avg
// outputs: [out0 fp32] ++ [avg fp32]

#define Bb 8
#define Tt 2048
#define Dd 2048
#define Mm (Bb * Tt)       // 16384
#define Kk 4096
#define NTK 128            // K-tiles of BK=32
#define NC 32
#define CT 64

typedef __bf16 bf16x8 __attribute__((ext_vector_type(8)));
typedef float f32x4 __attribute__((ext_vector_type(4)));

__device__ __forceinline__ void gload16(const void* g, void* l) {
    __builtin_amdgcn_global_load_lds(
        (const __attribute__((address_space(1))) unsigned int*)g,
        (__attribute__((address_space(3))) unsigned int*)l, 16, 0, 0);
}

// ---------------- K1: W fp32 -> bf16 ----------------
__global__ void wconv_kernel(const float* __restrict__ W,
                             unsigned short* __restrict__ Wb, long n) {
    long i = ((long)blockIdx.x * blockDim.x + threadIdx.x) * 4;
    long stride = (long)gridDim.x * blockDim.x * 4;
    for (; i < n; i += stride) {
        float4 v = *(const float4*)(W + i);
        __hip_bfloat16 a = __float2bfloat16(v.x);
        __hip_bfloat16 b = __float2bfloat16(v.y);
        __hip_bfloat16 c = __float2bfloat16(v.z);
        __hip_bfloat16 d = __float2bfloat16(v.w);
        ushort4 u;
        u.x = *(unsigned short*)&a; u.y = *(unsigned short*)&b;
        u.z = *(unsigned short*)&c; u.w = *(unsigned short*)&d;
        *(ushort4*)(Wb + i) = u;
    }
}

// ---------------- K2: per-chunk sums ----------------
__global__ void ksum_kernel(const float* __restrict__ X, float* __restrict__ S) {
    int d = blockIdx.y * 256 + threadIdx.x;
    int bc = blockIdx.x;
    int b = bc >> 5, c = bc & 31;
    const float* p = X + ((long)(b * Tt + c * CT)) * Dd + d;
    float s = 0.f;
#pragma unroll 8
    for (int t = 0; t < CT; ++t) s += p[(long)t * Dd];
    S[(long)bc * Dd + d] = s;
}

// ---------------- K3: scan + emit avg fp32 + gating_in bf16 ----------------
__global__ void kscan_kernel(const float* __restrict__ X, const float* __restrict__ S,
                             float* __restrict__ AVG, unsigned short* __restrict__ Gin) {
    int d = blockIdx.y * 256 + threadIdx.x;
    int bc = blockIdx.x;
    int b = bc >> 5, c = bc & 31;
    const float* Sp = S + (long)(b * NC) * Dd + d;
    float run = 0.f;
    for (int cc = 0; cc < c; ++cc) run += Sp[(long)cc * Dd];
    const float* p = X + ((long)(b * Tt + c * CT)) * Dd + d;
    long row = (long)b * Tt + c * CT;
    for (int tt = 0; tt < CT; ++tt) {
        float x = p[(long)tt * Dd];
        run += x;
        float av = run / (float)(c * CT + tt + 1);
        long r = row + tt;
        AVG[r * Dd + d] = av;
        __hip_bfloat16 xb = __float2bfloat16(x);
        __hip_bfloat16 ab = __float2bfloat16(av);
        Gin[r * 4096 + d] = *(unsigned short*)&xb;
        Gin[r * 4096 + 2048 + d] = *(unsigned short*)&ab;
    }
}

// ---------------- K4: 8-wave, BM=256 x 128 d-cols (dual gate), BK=32 ----------------
// 4-deep LDS ring (4 x 32KB), prefetch distance 3, counted vmcnt(8) at tile
// boundaries (never 0 in main loop). Chunk-XOR swizzle: LDS position chunk p of
// row r holds global chunk p ^ ((r>>1)&3); staging pre-swizzles the GLOBAL
// source (dest stays linear for global_load_lds), reads XOR the column.
#define MFMA(va, vb, c_) c_ = __builtin_amdgcn_mfma_f32_16x16x32_bf16(va, vb, c_, 0, 0, 0)
#define DS(p_, i_) (*(const bf16x8*)((p_) + (i_) * 1024))

#define TILE_BODY(t_, DO_ISSUE)                                                   \
  {                                                                               \
    const int buf_ = (t_) & 3;                                                    \
    const char* pa = rA + buf_ * 32768;                                           \
    const char* pb = rB + buf_ * 32768;                                           \
    bf16x8 a0 = DS(pa,0), a1 = DS(pa,1), a2 = DS(pa,2), a3 = DS(pa,3);            \
    bf16x8 b0 = DS(pb,0), b1 = DS(pb,1), b2 = DS(pb,2), b3 = DS(pb,3);            \
    if (DO_ISSUE) {                                                               \
      char* nd = ldsb + (((t_) + 3) & 3) * 32768 + woff;                          \
      const long ko = ((long)(t_) + 3) * 64;                                      \
      gload16(gA0 + ko, nd);                                                      \
      gload16(gA1 + ko, nd + 8192);                                               \
    }                                                                             \
    __builtin_amdgcn_s_setprio(1);                                                \
    MFMA(a0,b0,acc[0][0]); MFMA(a0,b1,acc[0][1]); MFMA(a0,b2,acc[0][2]); MFMA(a0,b3,acc[0][3]); \
    MFMA(a1,b0,acc[1][0]); MFMA(a1,b1,acc[1][1]); MFMA(a1,b2,acc[1][2]); MFMA(a1,b3,acc[1][3]); \
    MFMA(a2,b0,acc[2][0]); MFMA(a2,b1,acc[2][1]); MFMA(a2,b2,acc[2][2]); MFMA(a2,b3,acc[2][3]); \
    MFMA(a3,b0,acc[3][0]); MFMA(a3,b1,acc[3][1]); MFMA(a3,b2,acc[3][2]); MFMA(a3,b3,acc[3][3]); \
    __builtin_amdgcn_s_setprio(0);                                                \
    bf16x8 a4 = DS(pa,4), a5 = DS(pa,5), a6 = DS(pa,6), a7 = DS(pa,7);            \
    if (DO_ISSUE) {                                                               \
      char* nd = ldsb + (((t_) + 3) & 3) * 32768 + 16384 + woff;                  \
      const long ko = ((long)(t_) + 3) * 64;                                      \
      gload16(gB0 + ko, nd);                                                      \
      gload16(gB1 + ko, nd + 8192);                                               \
    }                                                                             \
    __builtin_amdgcn_s_setprio(1);                                                \
    MFMA(a4,b0,acc[4][0]); MFMA(a4,b1,acc[4][1]); MFMA(a4,b2,acc[4][2]); MFMA(a4,b3,acc[4][3]); \
    MFMA(a5,b0,acc[5][0]); MFMA(a5,b1,acc[5][1]); MFMA(a5,b2,acc[5][2]); MFMA(a5,b3,acc[5][3]); \
    MFMA(a6,b0,acc[6][0]); MFMA(a6,b1,acc[6][1]); MFMA(a6,b2,acc[6][2]); MFMA(a6,b3,acc[6][3]); \
    MFMA(a7,b0,acc[7][0]); MFMA(a7,b1,acc[7][1]); MFMA(a7,b2,acc[7][2]); MFMA(a7,b3,acc[7][3]); \
    __builtin_amdgcn_s_setprio(0);                                                \
  }

#define BOUNDARY(N_)                                                              \
  asm volatile("s_waitcnt vmcnt(" #N_ ")" ::: "memory");                          \
  __builtin_amdgcn_s_barrier();                                                   \
  __builtin_amdgcn_sched_barrier(0);

__global__ __launch_bounds__(512, 2) void gemm8_kernel(
    const unsigned short* __restrict__ Gin,  // [16384][4096] bf16
    const unsigned short* __restrict__ Wb,   // [4096][4096] bf16
    const float* __restrict__ bias,          // [4096]
    const float* __restrict__ X,             // [16384][2048]
    const float* __restrict__ AVG,           // [16384][2048]
    float* __restrict__ OUT)                 // [16384][2048]
{
    __shared__ char lds[131072];             // 4 bufs x (A 16KB + B 16KB)
    char* ldsb = (char*)lds;

    const int tid = threadIdx.x;
    const int w = tid >> 6, l = tid & 63;
    const int wm = w >> 2, wn = w & 3;       // 2(M) x 4(N) waves
    const int lm = l & 15;
    const int woff = w * 1024;

    // bijective XCD swizzle (1024 % 8 == 0): consecutive swz share the B panel
    const int bid = blockIdx.x;
    const int swz = (bid & 7) * 128 + (bid >> 3);
    const long m0 = (long)(swz & 63) * 256;
    const int n0 = (swz >> 6) * 128;

    // ---- staging addresses (pre-swizzled global chunk) ----
    const int srow = tid >> 2;                          // 0..127
    const int schunk = (tid & 3) ^ ((tid >> 3) & 3);    // = (tid&3) ^ ((row>>1)&3)
    const char* gA0 = (const char*)Gin + (m0 + srow) * 8192 + schunk * 16;
    const char* gA1 = gA0 + 128 * 8192;
    // B tile row j (0..255) -> W row: d-block (j>>6)*32 + (j&31), gate bit (j>>5)&1
    const long jr0 = n0 + ((srow >> 6) << 5) + (srow & 31) + (((srow >> 5) & 1) << 11);
    const int j1 = 128 + srow;
    const long jr1 = n0 + ((j1 >> 6) << 5) + (j1 & 31) + (((j1 >> 5) & 1) << 11);
    const char* gB0 = (const char*)Wb + jr0 * 8192 + schunk * 16;
    const char* gB1 = (const char*)Wb + jr1 * 8192 + schunk * 16;

    // ---- read addresses (swizzled column) ----
    const int cbyte = (((l >> 4) ^ ((lm >> 1) & 3))) * 16;
    const char* rA = ldsb + (wm * 128 + lm) * 64 + cbyte;           // + buf*32768 + mi*1024
    const char* rB = ldsb + 16384 + (wn * 64 + lm) * 64 + cbyte;    // + buf*32768 + ni*1024

    f32x4 acc[8][4] = {};

    // prologue: stage tiles 0,1,2 (order A0,A1,B0,B1 per tile — must match loop)
    {
        gload16(gA0,       ldsb + woff);
        gload16(gA1,       ldsb + 8192 + woff);
        gload16(gB0,       ldsb + 16384 + woff);
        gload16(gB1,       ldsb + 24576 + woff);
        gload16(gA0 + 64,  ldsb + 32768 + woff);
        gload16(gA1 + 64,  ldsb + 32768 + 8192 + woff);
        gload16(gB0 + 64,  ldsb + 32768 + 16384 + woff);
        gload16(gB1 + 64,  ldsb + 32768 + 24576 + woff);
        gload16(gA0 + 128, ldsb + 65536 + woff);
        gload16(gA1 + 128, ldsb + 65536 + 8192 + woff);
        gload16(gB0 + 128, ldsb + 65536 + 16384 + woff);
        gload16(gB1 + 128, ldsb + 65536 + 24576 + woff);
    }
    BOUNDARY(8);        // tile 0 ready; tiles 1,2 in flight

#pragma unroll 1
    for (int t = 0; t < NTK - 3; ++t) {   // t = 0..124, issues tiles 3..127
        TILE_BODY(t, 1);
        BOUNDARY(8);                      // t+1 ready; t+2, t+3 in flight
    }
    TILE_BODY(125, 0);
    BOUNDARY(4);                          // 126 ready; 127 in flight
    TILE_BODY(126, 0);
    BOUNDARY(0);                          // 127 ready (final drain)
    TILE_BODY(127, 0);

    // ---- fused epilogue ----
#pragma unroll
    for (int mi = 0; mi < 8; ++mi) {
        long rbase = m0 + wm * 128 + mi * 16 + (l >> 4) * 4;
#pragma unroll
        for (int nj = 0; nj < 2; ++nj) {
            int d = n0 + wn * 32 + nj * 16 + lm;
            float bi_ = bias[d];
            float bf_ = bias[d + 2048];
#pragma unroll
            for (int r = 0; r < 4; ++r) {
                long idx = (rbase + r) * 2048 + d;
                float gi = acc[mi][nj][r] + bi_;
                float gf = acc[mi][nj + 2][r] + bf_;
                float x = X[idx];
                float av = AVG[idx];
                float si = 1.f / (1.f + __expf(-gi));
                float sf = 1.f / (1.f + __expf(-gf));
                OUT[idx] = si * x + sf * av;
            }
        }
    }
}

extern "C" void kernel_launch(void* const* d_in, const int* in_sizes, int n_in,
                              void* d_out, int out_size, void* d_ws, size_t ws_size,
                              hipStream_t stream) {
    const float* X = (const float*)d_in[0];     // layer_in [8][2048][2048]
    const float* W = (const float*)d_in[1];     // W_gate [4096][4096]
    const float* bias = (const float*)d_in[2];  // b_gate [4096]

    float* OUT = (float*)d_out;                 // gating_out
    float* AVG = OUT + (long)Mm * Dd;           // average_out

    char* ws = (char*)d_ws;
    unsigned short* Wb  = (unsigned short*)ws;                    // 33,554,432 B
    unsigned short* Gin = (unsigned short*)(ws + 33554432);       // 134,217,728 B
    float* S = (float*)(ws + 33554432 + 134217728);               // 2,097,152 B

    wconv_kernel<<<2048, 256, 0, stream>>>(W, Wb, (long)Kk * Kk);
    ksum_kernel<<<dim3(Bb * NC, Dd / 256), 256, 0, stream>>>(X, S);
    kscan_kernel<<<dim3(Bb * NC, Dd / 256), 256, 0, stream>>>(X, S, AVG, Gin);
    gemm8_kernel<<<1024, 512, 0, stream>>>(Gin, Wb, bias, X, AVG, OUT);
}

// Round 3
// 690.016 us; speedup vs baseline: 1.1631x; 1.0002x over previous
//
#include <hip/hip_runtime.h>
#include <hip/hip_bf16.h>

// B=8, T=2048, D=2048.
//   avg = cumsum(x, axis=T) / (t+1)
//   gates = concat(x, avg) @ W^T + b    (W: [4096][4096])
//   out0 = sig(gates[:, :2048]) * x + sig(gates[:, 2048:]) * avg
// outputs: [out0 fp32] ++ [avg fp32]

#define Bb 8
#define Tt 2048
#define Dd 2048
#define Mm (Bb * Tt)       // 16384
#define Kk 4096
#define NTK 128            // K-tiles of BK=32
#define NC 32
#define CT 64

typedef __bf16 bf16x8 __attribute__((ext_vector_type(8)));
typedef float f32x16 __attribute__((ext_vector_type(16)));

__device__ __forceinline__ void gload16(const void* g, void* l) {
    __builtin_amdgcn_global_load_lds(
        (const __attribute__((address_space(1))) unsigned int*)g,
        (__attribute__((address_space(3))) unsigned int*)l, 16, 0, 0);
}

// ---------------- K1: W fp32 -> bf16 ----------------
__global__ void wconv_kernel(const float* __restrict__ W,
                             unsigned short* __restrict__ Wb, long n) {
    long i = ((long)blockIdx.x * blockDim.x + threadIdx.x) * 4;
    long stride = (long)gridDim.x * blockDim.x * 4;
    for (; i < n; i += stride) {
        float4 v = *(const float4*)(W + i);
        __hip_bfloat16 a = __float2bfloat16(v.x);
        __hip_bfloat16 b = __float2bfloat16(v.y);
        __hip_bfloat16 c = __float2bfloat16(v.z);
        __hip_bfloat16 d = __float2bfloat16(v.w);
        ushort4 u;
        u.x = *(unsigned short*)&a; u.y = *(unsigned short*)&b;
        u.z = *(unsigned short*)&c; u.w = *(unsigned short*)&d;
        *(ushort4*)(Wb + i) = u;
    }
}

// ---------------- K2: per-chunk sums ----------------
__global__ void ksum_kernel(const float* __restrict__ X, float* __restrict__ S) {
    int d = blockIdx.y * 256 + threadIdx.x;
    int bc = blockIdx.x;
    int b = bc >> 5, c = bc & 31;
    const float* p = X + ((long)(b * Tt + c * CT)) * Dd + d;
    float s = 0.f;
#pragma unroll 8
    for (int t = 0; t < CT; ++t) s += p[(long)t * Dd];
    S[(long)bc * Dd + d] = s;
}

// ---------------- K3: scan + emit avg fp32 + gating_in bf16 ----------------
__global__ void kscan_kernel(const float* __restrict__ X, const float* __restrict__ S,
                             float* __restrict__ AVG, unsigned short* __restrict__ Gin) {
    int d = blockIdx.y * 256 + threadIdx.x;
    int bc = blockIdx.x;
    int b = bc >> 5, c = bc & 31;
    const float* Sp = S + (long)(b * NC) * Dd + d;
    float run = 0.f;
    for (int cc = 0; cc < c; ++cc) run += Sp[(long)cc * Dd];
    const float* p = X + ((long)(b * Tt + c * CT)) * Dd + d;
    long row = (long)b * Tt + c * CT;
    for (int tt = 0; tt < CT; ++tt) {
        float x = p[(long)tt * Dd];
        run += x;
        float av = run / (float)(c * CT + tt + 1);
        long r = row + tt;
        AVG[r * Dd + d] = av;
        __hip_bfloat16 xb = __float2bfloat16(x);
        __hip_bfloat16 ab = __float2bfloat16(av);
        Gin[r * 4096 + d] = *(unsigned short*)&xb;
        Gin[r * 4096 + 2048 + d] = *(unsigned short*)&ab;
    }
}

// ---------------- K4: 8-wave, 256 rows x 128 d-cols (dual gate), BK=32 ------
// mfma_f32_32x32x16_bf16, 2 phases/K-tile + counted-vmcnt boundary.
// 4-deep LDS ring (4 x 32KB), prefetch distance 3, vmcnt(8) (never 0 in loop).
// Chunk-XOR swizzle s(r) = (r>>1)&3: stored chunk p of row r holds global
// chunk p ^ s(r); staging pre-swizzles the GLOBAL source (LDS dest stays
// linear for global_load_lds), reads XOR the chunk index.
#define MFMA32(va, vb, c_) c_ = __builtin_amdgcn_mfma_f32_32x32x16_bf16(va, vb, c_, 0, 0, 0)
#define RD(p_, i_) (*(const bf16x8*)((p_) + (i_) * 2048))

// One phase: 6 ds_read (4 A-frags + 2 B-frags at k-step kk_), optional 2
// global_load_lds (A- or B-half of tile t+3), barrier, 8 MFMA.
#define PH(t_, kk_, IA_, IB_)                                                   \
  {                                                                             \
    const int buf_ = (t_) & 3;                                                  \
    const char* pa_ = ((kk_) ? rA1 : rA0) + buf_ * 32768;                       \
    const char* pb_ = ((kk_) ? rB1 : rB0) + buf_ * 32768;                       \
    bf16x8 a0 = RD(pa_,0), a1 = RD(pa_,1), a2 = RD(pa_,2), a3 = RD(pa_,3);      \
    bf16x8 b0 = RD(pb_,0), b1 = RD(pb_,1);                                      \
    if (IA_) { char* nd_ = ldsb + (((t_)+3)&3)*32768 + woff;                    \
      const long ko_ = ((long)(t_)+3)*64;                                       \
      gload16(gA0 + ko_, nd_); gload16(gA1 + ko_, nd_ + 8192); }                \
    if (IB_) { char* nd_ = ldsb + (((t_)+3)&3)*32768 + 16384 + woff;            \
      const long ko_ = ((long)(t_)+3)*64;                                       \
      gload16(gB0 + ko_, nd_); gload16(gB1 + ko_, nd_ + 8192); }                \
    __builtin_amdgcn_s_barrier();                                               \
    __builtin_amdgcn_sched_barrier(0);                                          \
    __builtin_amdgcn_s_setprio(1);                                              \
    MFMA32(a0, b0, acc[0][0]); MFMA32(a0, b1, acc[0][1]);                       \
    MFMA32(a1, b0, acc[1][0]); MFMA32(a1, b1, acc[1][1]);                       \
    MFMA32(a2, b0, acc[2][0]); MFMA32(a2, b1, acc[2][1]);                       \
    MFMA32(a3, b0, acc[3][0]); MFMA32(a3, b1, acc[3][1]);                       \
    __builtin_amdgcn_s_setprio(0);                                              \
    __builtin_amdgcn_sched_barrier(0);                                          \
  }

#define BOUNDARY(N_)                                                            \
  asm volatile("s_waitcnt vmcnt(" #N_ ")" ::: "memory");                        \
  __builtin_amdgcn_s_barrier();                                                 \
  __builtin_amdgcn_sched_barrier(0);

__global__ __launch_bounds__(512, 2) void gemm32_kernel(
    const unsigned short* __restrict__ Gin,  // [16384][4096] bf16
    const unsigned short* __restrict__ Wb,   // [4096][4096] bf16
    const float* __restrict__ bias,          // [4096]
    const float* __restrict__ X,             // [16384][2048]
    const float* __restrict__ AVG,           // [16384][2048]
    float* __restrict__ OUT)                 // [16384][2048]
{
    __shared__ __attribute__((aligned(128))) char lds[131072]; // 4 x (A 16KB + B 16KB)
    char* ldsb = (char*)lds;

    const int tid = threadIdx.x;
    const int w = tid >> 6, l = tid & 63;
    const int wm = w >> 2, wn = w & 3;       // 2(M) x 4(N) waves
    const int la = l & 31;                   // fragment row/col within 32
    const int lk = l >> 5;                   // k half-group
    const int woff = w * 1024;

    // Batch-aware mapping: concurrent 256 blocks = 16 m-tiles x all 16 n-tiles
    // (A 32MB + W 32MB < L3). Per XCD (bid&7): 2 n-tiles -> B panel 4MB in L2.
    const int bid = blockIdx.x;
    const int batch = bid >> 8;              // 0..3
    const int rr = bid & 255;
    const int xcd = rr & 7;
    const int j = rr >> 3;                   // 0..31
    const int nt = xcd * 2 + (j >> 4);       // 0..15
    const int mt = batch * 16 + (j & 15);    // 0..63
    const long m0 = (long)mt * 256;
    const int n0 = nt * 128;

    // ---- staging addresses (pre-swizzled global chunk) ----
    const int srow = tid >> 2;                          // 0..127
    const int schunk = (tid & 3) ^ ((tid >> 3) & 3);    // p ^ s(row), row=tid>>2
    const char* gA0 = (const char*)Gin + (m0 + srow) * 8192 + schunk * 16;
    const char* gA1 = gA0 + 128 * 8192;
    // B tile row j (0..255) -> W row: d-block (j>>6)*32 + (j&31), gate (j>>5)&1
    const long jr0 = n0 + ((srow >> 6) << 5) + (srow & 31) + (((srow >> 5) & 1) << 11);
    const int j1 = 128 + srow;
    const long jr1 = n0 + ((j1 >> 6) << 5) + (j1 & 31) + (((j1 >> 5) & 1) << 11);
    const char* gB0 = (const char*)Wb + jr0 * 8192 + schunk * 16;
    const char* gB1 = (const char*)Wb + jr1 * 8192 + schunk * 16;

    // ---- read addresses: row r, logical chunk q=(kk*2+lk) at pos q^((r>>1)&3) ----
    const int cb0 = ((lk ^ ((la >> 1) & 3))) * 16;      // kk=0
    const int cb1 = cb0 ^ 32;                           // kk=1 (flip chunk bit 1)
    const char* rA0 = ldsb + (wm * 128 + la) * 64 + cb0;          // + buf*32768 + mi*2048
    const char* rA1 = ldsb + (wm * 128 + la) * 64 + cb1;
    const char* rB0 = ldsb + 16384 + (wn * 64 + la) * 64 + cb0;   // + buf*32768 + ni*2048
    const char* rB1 = ldsb + 16384 + (wn * 64 + la) * 64 + cb1;

    f32x16 acc[4][2] = {};   // [mi][ni]; ni=0 input gate, ni=1 forget gate

    // prologue: stage tiles 0,1,2 (per tile: A0,A1,B0,B1 — matches loop order)
    {
        gload16(gA0,       ldsb + woff);
        gload16(gA1,       ldsb + 8192 + woff);
        gload16(gB0,       ldsb + 16384 + woff);
        gload16(gB1,       ldsb + 24576 + woff);
        gload16(gA0 + 64,  ldsb + 32768 + woff);
        gload16(gA1 + 64,  ldsb + 32768 + 8192 + woff);
        gload16(gB0 + 64,  ldsb + 32768 + 16384 + woff);
        gload16(gB1 + 64,  ldsb + 32768 + 24576 + woff);
        gload16(gA0 + 128, ldsb + 65536 + woff);
        gload16(gA1 + 128, ldsb + 65536 + 8192 + woff);
        gload16(gB0 + 128, ldsb + 65536 + 16384 + woff);
        gload16(gB1 + 128, ldsb + 65536 + 24576 + woff);
    }
    BOUNDARY(8);        // tile 0 ready; tiles 1,2 in flight

#pragma unroll 1
    for (int t = 0; t < NTK - 3; ++t) {   // t = 0..124, issues tiles 3..127
        PH(t, 0, 1, 0);
        PH(t, 1, 0, 1);
        BOUNDARY(8);                      // t+1 ready; t+2, t+3 in flight
    }
    PH(125, 0, 0, 0); PH(125, 1, 0, 0);
    BOUNDARY(4);                          // 126 ready; 127 in flight
    PH(126, 0, 0, 0); PH(126, 1, 0, 0);
    BOUNDARY(0);                          // 127 ready (final drain)
    PH(127, 0, 0, 0); PH(127, 1, 0, 0);

    // ---- fused epilogue ----
    // C/D (32x32): col = lane&31, row = (q&3) + 8*(q>>2) + 4*(lane>>5)
    const int d = n0 + wn * 32 + la;
    const float bi_ = bias[d];
    const float bf_ = bias[d + 2048];
#pragma unroll
    for (int mi = 0; mi < 4; ++mi) {
        const long rb = m0 + wm * 128 + mi * 32 + lk * 4;
        f32x16 ci = acc[mi][0];
        f32x16 cf = acc[mi][1];
#pragma unroll
        for (int q = 0; q < 16; ++q) {
            long row = rb + (q & 3) + 8 * (q >> 2);
            long idx = row * 2048 + d;
            float gi = ci[q] + bi_;
            float gf = cf[q] + bf_;
            float x = X[idx];
            float av = AVG[idx];
            float si = 1.f / (1.f + __expf(-gi));
            float sf = 1.f / (1.f + __expf(-gf));
            OUT[idx] = si * x + sf * av;
        }
    }
}

extern "C" void kernel_launch(void* const* d_in, const int* in_sizes, int n_in,
                              void* d_out, int out_size, void* d_ws, size_t ws_size,
                              hipStream_t stream) {
    const float* X = (const float*)d_in[0];     // layer_in [8][2048][2048]
    const float* W = (const float*)d_in[1];     // W_gate [4096][4096]
    const float* bias = (const float*)d_in[2];  // b_gate [4096]

    float* OUT = (float*)d_out;                 // gating_out
    float* AVG = OUT + (long)Mm * Dd;           // average_out

    char* ws = (char*)d_ws;
    unsigned short* Wb  = (unsigned short*)ws;                    // 33,554,432 B
    unsigned short* Gin = (unsigned short*)(ws + 33554432);       // 134,217,728 B
    float* S = (float*)(ws + 33554432 + 134217728);               // 2,097,152 B

    wconv_kernel<<<2048, 256, 0, stream>>>(W, Wb, (long)Kk * Kk);
    ksum_kernel<<<dim3(Bb * NC, Dd / 256), 256, 0, stream>>>(X, S);
    kscan_kernel<<<dim3(Bb * NC, Dd / 256), 256, 0, stream>>>(X, S, AVG, Gin);
    gemm32_kernel<<<1024, 512, 0, stream>>>(Gin, Wb, bias, X, AVG, OUT);
}